// Round 5
// baseline (312.501 us; speedup 1.0000x reference)
//
#include <hip/hip_runtime.h>
#include <math.h>

constexpr int BATCH = 8;
constexpr int NC    = 384;
constexpr int H     = 56, W = 56, HW = 3136;
constexpr int NPTS  = 784;          // 28*28
constexpr int NG    = 4, GC = 96;
constexpr int NH    = 8, HC = 48;

typedef __attribute__((ext_vector_type(8))) short short8;
typedef __attribute__((ext_vector_type(4))) float f32x4;
typedef __attribute__((ext_vector_type(4))) unsigned short us4;

__device__ inline unsigned short f2bf(float f) {       // RNE
    union { float f; unsigned u; } v; v.f = f;
    unsigned r = v.u + 0x7FFF + ((v.u >> 16) & 1);
    return (unsigned short)(r >> 16);
}
__device__ inline float bf2f(unsigned short u) {
    union { unsigned u; float f; } v; v.u = (unsigned)u << 16;
    return v.f;
}
__device__ inline float wred_sum(float v) {
    #pragma unroll
    for (int off = 32; off > 0; off >>= 1) v += __shfl_xor(v, off);
    return v;
}

// ---------------------------------------------------------------------------
// Transpose+convert: x [b][384][3136] fp32 -> xT [b][3136][384] bf16
// ---------------------------------------------------------------------------
__global__ __launch_bounds__(256) void transpose_cvt(
    const float* __restrict__ x, unsigned short* __restrict__ xT)
{
    __shared__ unsigned short Ls[64 * 68];
    int b = blockIdx.z, c0 = blockIdx.y * 64, hw0 = blockIdx.x * 64;
    const float* xb = x + ((size_t)b * NC + c0) * HW + hw0;
    int t = threadIdx.x;
    #pragma unroll
    for (int i = 0; i < 4; i++) {
        int u = t + i * 256;
        int cc = u >> 4, f4 = (u & 15) * 4;
        float4 v = *(const float4*)&xb[(size_t)cc * HW + f4];
        us4 p; p[0] = f2bf(v.x); p[1] = f2bf(v.y); p[2] = f2bf(v.z); p[3] = f2bf(v.w);
        *(us4*)&Ls[cc * 68 + f4] = p;
    }
    __syncthreads();
    unsigned short* xTb = xT + ((size_t)b * HW + hw0) * NC + c0;
    #pragma unroll
    for (int i = 0; i < 4; i++) {
        int u = t + i * 256;
        int hw = u >> 4, cg = (u & 15) * 4;
        us4 p;
        p[0] = Ls[(cg + 0) * 68 + hw];
        p[1] = Ls[(cg + 1) * 68 + hw];
        p[2] = Ls[(cg + 2) * 68 + hw];
        p[3] = Ls[(cg + 3) * 68 + hw];
        *(us4*)&xTb[(size_t)hw * NC + cg] = p;
    }
}

// ---------------------------------------------------------------------------
// Weight convert: Wq -> wqb, Wk -> wkv[0:384], Wv -> wkv[384:768], Wo -> wob
// ---------------------------------------------------------------------------
__global__ __launch_bounds__(256) void wcvt(
    const float* __restrict__ w0, const float* __restrict__ w1,
    const float* __restrict__ w2, const float* __restrict__ w3,
    unsigned short* __restrict__ o0, unsigned short* __restrict__ okv,
    unsigned short* __restrict__ o3)
{
    const float* src; unsigned short* dst;
    switch (blockIdx.y) {
        case 0: src = w0; dst = o0; break;
        case 1: src = w1; dst = okv; break;
        case 2: src = w2; dst = okv + NC * NC; break;
        default: src = w3; dst = o3; break;
    }
    int idx = (blockIdx.x * 256 + threadIdx.x) * 4;
    float4 v = *(const float4*)&src[idx];
    us4 p; p[0] = f2bf(v.x); p[1] = f2bf(v.y); p[2] = f2bf(v.z); p[3] = f2bf(v.w);
    *(us4*)&dst[idx] = p;
}

// ---------------------------------------------------------------------------
// bf16 MFMA GEMM: C[b][m][n] = A[m][k] * BT[b][n][k]^T + bias[m]
// MODE 0: fp32 out [m][n]
// MODE 2: bf16 T-out [n][384]
// MODE 4: fused KV (A is 768 rows): m<384 -> KT[n][384] (bias), m>=384 ->
//         V[m-384][n] (bias2) into Cb2
// v2: register-prefetch pipeline (issue k+1 global loads after the barrier,
// before compute of k) — the N=3136 gemms run at only ~2.3 blocks/CU, so the
// previous serial load->LDS->sync->compute chain exposed ~900cy of HBM
// latency on every one of the 12 K-iters.
// ---------------------------------------------------------------------------
template<int MODE>
__global__ __launch_bounds__(256) void gemm_bf16(
    const unsigned short* __restrict__ A, const float* __restrict__ bias,
    const float* __restrict__ bias2, const unsigned short* __restrict__ BT,
    float* __restrict__ Cf, unsigned short* __restrict__ Cb,
    unsigned short* __restrict__ Cb2, int N)
{
    int b  = blockIdx.z;
    int n0 = blockIdx.x * 128;
    int m0 = blockIdx.y * 128;
    const unsigned short* BTb = BT + (size_t)b * N * NC;

    __shared__ unsigned short As[128 * 40];
    __shared__ unsigned short Bs[128 * 40];

    int t = threadIdx.x;
    int wave = t >> 6, lane = t & 63;
    int quad = lane >> 4, col = lane & 15;
    int wm = (wave >> 1) * 64, wn = (wave & 1) * 64;

    const short8 z8 = {0,0,0,0,0,0,0,0};
    f32x4 acc[4][4];
    #pragma unroll
    for (int i = 0; i < 4; i++)
        #pragma unroll
        for (int j = 0; j < 4; j++) acc[i][j] = (f32x4){0.f, 0.f, 0.f, 0.f};

    short8 areg[2], breg[2];
    auto stage_load = [&](int k0) {
        #pragma unroll
        for (int i = 0; i < 2; i++) {
            int u = t + i * 256;
            int mmi = u >> 2, kci = (u & 3) * 8;
            areg[i] = *(const short8*)&A[(size_t)(m0 + mmi) * NC + k0 + kci];
            short8 val = z8;
            if (n0 + mmi < N)
                val = *(const short8*)&BTb[(size_t)(n0 + mmi) * NC + k0 + kci];
            breg[i] = val;
        }
    };

    stage_load(0);
    for (int k0 = 0; k0 < NC; k0 += 32) {
        #pragma unroll
        for (int i = 0; i < 2; i++) {
            int u = t + i * 256;
            int mmi = u >> 2, kci = (u & 3) * 8;
            *(short8*)&As[mmi * 40 + kci] = areg[i];
            *(short8*)&Bs[mmi * 40 + kci] = breg[i];
        }
        __syncthreads();
        if (k0 + 32 < NC) stage_load(k0 + 32);   // prefetch next K-tile

        short8 af[4], bf[4];
        #pragma unroll
        for (int mt = 0; mt < 4; mt++)
            af[mt] = *(const short8*)&As[(wm + mt * 16 + col) * 40 + quad * 8];
        #pragma unroll
        for (int nt = 0; nt < 4; nt++)
            bf[nt] = *(const short8*)&Bs[(wn + nt * 16 + col) * 40 + quad * 8];
        #pragma unroll
        for (int mt = 0; mt < 4; mt++)
            #pragma unroll
            for (int nt = 0; nt < 4; nt++)
                acc[mt][nt] = __builtin_amdgcn_mfma_f32_16x16x32_bf16(
                    af[mt], bf[nt], acc[mt][nt], 0, 0, 0);
        __syncthreads();
    }

    if constexpr (MODE == 0) {
        float* Cfb = Cf + (size_t)b * NC * N;
        #pragma unroll
        for (int mt = 0; mt < 4; mt++) {
            #pragma unroll
            for (int r = 0; r < 4; r++) {
                int m = m0 + wm + mt * 16 + quad * 4 + r;
                float bv = bias[m];
                #pragma unroll
                for (int nt = 0; nt < 4; nt++) {
                    int n = n0 + wn + nt * 16 + col;
                    if (n < N) Cfb[(size_t)m * N + n] = acc[mt][nt][r] + bv;
                }
            }
        }
    } else if constexpr (MODE == 2) {
        unsigned short* Kb = Cb + (size_t)b * N * NC;
        #pragma unroll
        for (int mt = 0; mt < 4; mt++) {
            int mb = m0 + wm + mt * 16 + quad * 4;
            float bv[4];
            #pragma unroll
            for (int r = 0; r < 4; r++) bv[r] = bias[mb + r];
            #pragma unroll
            for (int nt = 0; nt < 4; nt++) {
                int n = n0 + wn + nt * 16 + col;
                if (n < N) {
                    us4 p;
                    #pragma unroll
                    for (int r = 0; r < 4; r++) p[r] = f2bf(acc[mt][nt][r] + bv[r]);
                    *(us4*)&Kb[(size_t)n * NC + mb] = p;
                }
            }
        }
    } else {   // MODE 4: fused KV
        if (m0 < NC) {     // K rows -> KT[n][384]
            unsigned short* Kb = Cb + (size_t)b * N * NC;
            #pragma unroll
            for (int mt = 0; mt < 4; mt++) {
                int mb = m0 + wm + mt * 16 + quad * 4;
                float bv[4];
                #pragma unroll
                for (int r = 0; r < 4; r++) bv[r] = bias[mb + r];
                #pragma unroll
                for (int nt = 0; nt < 4; nt++) {
                    int n = n0 + wn + nt * 16 + col;
                    if (n < N) {
                        us4 p;
                        #pragma unroll
                        for (int r = 0; r < 4; r++) p[r] = f2bf(acc[mt][nt][r] + bv[r]);
                        *(us4*)&Kb[(size_t)n * NC + mb] = p;
                    }
                }
            }
        } else {           // V rows -> V[m-384][n]
            unsigned short* Vb = Cb2 + (size_t)b * NC * N;
            #pragma unroll
            for (int mt = 0; mt < 4; mt++) {
                #pragma unroll
                for (int r = 0; r < 4; r++) {
                    int m = m0 - NC + wm + mt * 16 + quad * 4 + r;
                    float bv = bias2[m];
                    #pragma unroll
                    for (int nt = 0; nt < 4; nt++) {
                        int n = n0 + wn + nt * 16 + col;
                        if (n < N) Vb[(size_t)m * N + n] = f2bf(acc[mt][nt][r] + bv);
                    }
                }
            }
        }
    }
}

// ---------------------------------------------------------------------------
// Offset net, wave-per-point (unchanged)
// ---------------------------------------------------------------------------
__global__ __launch_bounds__(256) void offset_kernel(
    const unsigned short* __restrict__ qT, const float* __restrict__ dww,
    const float* __restrict__ dwb, const float* __restrict__ lng,
    const float* __restrict__ lnb, const float* __restrict__ pww,
    float* __restrict__ pos_out,   float* __restrict__ ref_out)
{
    int wave = threadIdx.x >> 6, l = threadIdx.x & 63;
    int bg = blockIdx.y, b = bg >> 2, g = bg & 3;
    int s  = blockIdx.x * 4 + wave;
    int py = s / 28, px = s - py * 28;
    bool has2 = l < 32;
    int c0 = l, c1 = 64 + l;

    const unsigned short* qb = qT + (size_t)b * HW * NC + g * GC;

    float h0 = 0.f, h1 = 0.f;
    #pragma unroll
    for (int ky = 0; ky < 3; ky++) {
        int yy = py * 2 - 1 + ky;
        if (yy < 0 || yy >= H) continue;
        #pragma unroll
        for (int kx = 0; kx < 3; kx++) {
            int xx = px * 2 - 1 + kx;
            if (xx < 0 || xx >= W) continue;
            const unsigned short* row = qb + (size_t)(yy * W + xx) * NC;
            float w0 = dww[c0 * 9 + ky * 3 + kx];
            h0 = fmaf(bf2f(row[c0]), w0, h0);
            if (has2) {
                float w1 = dww[c1 * 9 + ky * 3 + kx];
                h1 = fmaf(bf2f(row[c1]), w1, h1);
            }
        }
    }
    h0 += dwb[c0];
    if (has2) h1 += dwb[c1];

    float mu = wred_sum(h0 + (has2 ? h1 : 0.f)) * (1.f / GC);
    float d0 = h0 - mu, d1 = h1 - mu;
    float var = wred_sum(d0 * d0 + (has2 ? d1 * d1 : 0.f)) * (1.f / GC);
    float rstd = rsqrtf(var + 1e-5f);

    float hn0 = d0 * rstd * lng[c0] + lnb[c0];
    float ge0 = 0.5f * hn0 * (1.f + erff(hn0 * 0.70710678118654752f));
    float ge1 = 0.f;
    if (has2) {
        float hn1 = d1 * rstd * lng[c1] + lnb[c1];
        ge1 = 0.5f * hn1 * (1.f + erff(hn1 * 0.70710678118654752f));
    }

    float offy = wred_sum(ge0 * pww[c0] + (has2 ? ge1 * pww[c1] : 0.f));
    float offx = wred_sum(ge0 * pww[GC + c0] + (has2 ? ge1 * pww[GC + c1] : 0.f));

    if (l == 0) {
        float ry = (2.f * py + 1.f) / 27.f - 1.f;
        float rx = (2.f * px + 1.f) / 27.f - 1.f;
        size_t idx = ((size_t)bg * NPTS + s) * 2;
        pos_out[idx]     = tanhf(offy) * (1.f / 27.f) + ry;
        pos_out[idx + 1] = tanhf(offx) * (1.f / 27.f) + rx;
        ref_out[idx]     = ry;
        ref_out[idx + 1] = rx;
    }
}

// ---------------------------------------------------------------------------
// Bilinear grid sample from xT (bf16, [b][hw][384]) -> xsT [b][pt][384] bf16.
// v2: us4 vector loads (24 active lanes x 8B) instead of 12 scalar 2B
// gathers per lane (Common-mistake #2).
// ---------------------------------------------------------------------------
__global__ __launch_bounds__(256) void sample_kernel(
    const unsigned short* __restrict__ xT, const float* __restrict__ pos,
    unsigned short* __restrict__ xsT)
{
    int bg = blockIdx.y;
    int b  = bg >> 2, g = bg & 3;
    int s  = blockIdx.x * 8 + (threadIdx.x >> 5);
    int l  = threadIdx.x & 31;

    const float* pg = pos + ((size_t)bg * NPTS + s) * 2;
    float py = pg[0], px = pg[1];
    float gx = (px + 1.f) * 27.5f;
    float gy = (py + 1.f) * 27.5f;
    float x0f = floorf(gx), y0f = floorf(gy);
    int ix0 = (int)x0f, iy0 = (int)y0f;
    int ix1 = ix0 + 1,  iy1 = iy0 + 1;
    float wx1 = gx - x0f, wx0 = 1.f - wx1;
    float wy1 = gy - y0f, wy0 = 1.f - wy1;
    bool vx0 = (ix0 >= 0) && (ix0 < W);
    bool vx1 = (ix1 >= 0) && (ix1 < W);
    bool vy0 = (iy0 >= 0) && (iy0 < H);
    bool vy1 = (iy1 >= 0) && (iy1 < H);
    int cx0 = vx0 ? ix0 : 0, cx1 = vx1 ? ix1 : 0;
    int cy0 = vy0 ? iy0 : 0, cy1 = vy1 ? iy1 : 0;
    float w00 = (vx0 && vy0) ? wx0 * wy0 : 0.f;
    float w01 = (vx1 && vy0) ? wx1 * wy0 : 0.f;
    float w10 = (vx0 && vy1) ? wx0 * wy1 : 0.f;
    float w11 = (vx1 && vy1) ? wx1 * wy1 : 0.f;

    if (l < 24) {
        const unsigned short* xb = xT + (size_t)b * HW * NC + g * GC;
        const unsigned short* r00 = xb + (size_t)(cy0 * W + cx0) * NC + l * 4;
        const unsigned short* r01 = xb + (size_t)(cy0 * W + cx1) * NC + l * 4;
        const unsigned short* r10 = xb + (size_t)(cy1 * W + cx0) * NC + l * 4;
        const unsigned short* r11 = xb + (size_t)(cy1 * W + cx1) * NC + l * 4;
        us4 a00 = *(const us4*)r00;
        us4 a01 = *(const us4*)r01;
        us4 a10 = *(const us4*)r10;
        us4 a11 = *(const us4*)r11;
        us4 o;
        #pragma unroll
        for (int j = 0; j < 4; j++) {
            float val = bf2f(a00[j]) * w00 + bf2f(a01[j]) * w01
                      + bf2f(a10[j]) * w10 + bf2f(a11[j]) * w11;
            o[j] = f2bf(val);
        }
        *(us4*)&xsT[((size_t)b * NPTS + s) * NC + g * GC + l * 4] = o;
    }
}

// ---------------------------------------------------------------------------
// Fused flash attention v10: v9 structure (128 q/block, in-register P,
// l folded into PV via ones-row tile, v_perm pack) with two fixes from the
// R4 post-mortem:
//  (a) exp2f (libm ocml path, ~7 VALU ops incl. range handling) replaced by
//      __builtin_amdgcn_exp2f = one raw v_exp_f32. |S*scale*log2e| is tiny
//      here (0.02-scale weights), so the precise path's range handling is
//      dead weight. Biggest remaining VALU consumer (16 calls/32-key step).
//  (b) KS_STRIDE 56 -> 60 shorts: K-staging writes had byte stride 112
//      (bank step 28, gcd(28,32)=4 -> 4-way conflict, 1.58x); stride 120
//      gives bank step 30 (gcd=2 -> 2-way, free per m136).
// ---------------------------------------------------------------------------
#define KS_STRIDE 60    // shorts: 48 chans + 12 pad (bank step 30 = 2-way)
#define VS_STRIDE 136   // shorts: 128 keys + 8 pad

__device__ inline short8 scale8(short8 v, float s) {
    short8 r;
    #pragma unroll
    for (int j = 0; j < 8; j++) {
        unsigned short b = (unsigned short)v[j];
        r[j] = (short)f2bf(bf2f(b) * s);
    }
    return r;
}

union pun8 { short8 s8; unsigned u[4]; };

__global__ __launch_bounds__(256) void attn_mfma(
    const unsigned short* __restrict__ qT, const unsigned short* __restrict__ kt,
    const unsigned short* __restrict__ vt, unsigned short* __restrict__ aoT)
{
    __shared__ __align__(16) unsigned short smem[128 * KS_STRIDE + 48 * VS_STRIDE];
    unsigned short* Ks = smem;                 // 128*60 = 7680 shorts
    unsigned short* Vs = Ks + 128 * KS_STRIDE; // 48*136 = 6528 shorts

    int t    = threadIdx.x;
    int wave = t >> 6, lane = t & 63;
    int quad = lane >> 4, col = lane & 15;

    int bh = blockIdx.y;
    int b  = bh >> 3, h = bh & 7;
    int m0 = blockIdx.x * 128;
    const unsigned short* KT = kt + (size_t)b * NPTS * NC + h * HC;
    const unsigned short* VT = vt + ((size_t)b * NC + h * HC) * NPTS;

    // 48^-0.5 * log2(e): QK MFMA then computes S*scale*log2e, so exp2(S') = exp(S*scale)
    const float scale = 0.14433756729740643f * 1.4426950408889634f;
    const short8 z8 = {0,0,0,0,0,0,0,0};

    // ---- ones-row A fragment for the l-accumulating PV tile ----
    short ones_v = (col == 0) ? (short)0x3F80 : (short)0;
    short8 ones8 = {ones_v, ones_v, ones_v, ones_v, ones_v, ones_v, ones_v, ones_v};

    // ---- Q B-fragments, 2 sets, pre-scaled ----
    int gmq[2];
    short8 qb0[2], qb1[2];
    #pragma unroll
    for (int set = 0; set < 2; set++) {
        int gm = m0 + wave * 32 + set * 16 + col;
        gmq[set] = gm;
        int cg = gm < HW ? gm : HW - 1;
        const unsigned short* r0 = qT + ((size_t)b * HW + cg) * NC + h * HC;
        qb0[set] = scale8(*(const short8*)&r0[quad * 8], scale);
        qb1[set] = (quad < 2) ? scale8(*(const short8*)&r0[32 + quad * 8], scale) : z8;
    }

    f32x4 acc_l[2];
    f32x4 acc_o[2][3];
    #pragma unroll
    for (int set = 0; set < 2; set++) {
        acc_l[set] = (f32x4){0.f, 0.f, 0.f, 0.f};
        #pragma unroll
        for (int ct = 0; ct < 3; ct++) acc_o[set][ct] = (f32x4){0.f, 0.f, 0.f, 0.f};
    }

    // staging identity: K key = t>>1 (0..127), parts (t&1)*3 ..+2
    int skey  = t >> 1;
    int spart = (t & 1) * 3;
    short8 kreg[3], vreg[3];

    // ---- prologue: load chunk 0 ----
    {
        const unsigned short* krow = KT + (size_t)skey * NC + spart * 8;
        #pragma unroll
        for (int i = 0; i < 3; i++) kreg[i] = *(const short8*)(krow + i * 8);
        #pragma unroll
        for (int i = 0; i < 3; i++) {
            int li = t + i * 256;
            int chan = li >> 4, part = li & 15;
            vreg[i] = *(const short8*)&VT[(size_t)chan * NPTS + part * 8];
        }
    }

    for (int ci = 0; ci < 7; ci++) {
        int k0 = ci * 128;

        // ---- write staged regs -> LDS ----
        #pragma unroll
        for (int i = 0; i < 3; i++)
            *(short8*)&Ks[skey * KS_STRIDE + (spart + i) * 8] = kreg[i];
        #pragma unroll
        for (int i = 0; i < 3; i++) {
            int li = t + i * 256;
            int chan = li >> 4, part = li & 15;
            *(short8*)&Vs[chan * VS_STRIDE + part * 8] = vreg[i];
        }
        __syncthreads();

        // ---- issue next chunk's global loads (latency hidden by compute) --
        if (ci < 6) {
            int nk0 = k0 + 128;
            bool kv = nk0 + skey < NPTS;
            const unsigned short* krow = KT + (size_t)(nk0 + skey) * NC + spart * 8;
            #pragma unroll
            for (int i = 0; i < 3; i++) kreg[i] = kv ? *(const short8*)(krow + i * 8) : z8;
            #pragma unroll
            for (int i = 0; i < 3; i++) {
                int li = t + i * 256;
                int chan = li >> 4, part = li & 15;
                vreg[i] = (nk0 + part * 8 < NPTS)
                    ? *(const short8*)&VT[(size_t)chan * NPTS + nk0 + part * 8] : z8;
            }
        }

        // ---- compute chunk ci ----
        #pragma unroll
        for (int s2 = 0; s2 < 4; s2++) {
            if (k0 + s2 * 32 < NPTS) {     // tail guard: skip dead 32-key steps
                unsigned pkd[2][2][2];
                #pragma unroll
                for (int jth = 0; jth < 2; jth++) {
                    int jt = s2 * 2 + jth;
                    int keyl = jt * 16 + col;
                    short8 kb0 = *(const short8*)&Ks[keyl * KS_STRIDE + quad * 8];
                    short8 kb1 = (quad < 2)
                        ? *(const short8*)&Ks[keyl * KS_STRIDE + 32 + quad * 8] : z8;
                    bool valid = (k0 + jt * 16) < NPTS;     // tile-uniform
                    #pragma unroll
                    for (int set = 0; set < 2; set++) {
                        f32x4 sa = {0.f, 0.f, 0.f, 0.f};
                        sa = __builtin_amdgcn_mfma_f32_16x16x32_bf16(kb0, qb0[set], sa, 0, 0, 0);
                        sa = __builtin_amdgcn_mfma_f32_16x16x32_bf16(kb1, qb1[set], sa, 0, 0, 0);
                        unsigned d0 = 0, d1 = 0;
                        if (valid) {
                            union { float f; unsigned u; } e0, e1, e2, e3;
                            e0.f = __builtin_amdgcn_exp2f(sa[0]);   // raw v_exp_f32
                            e1.f = __builtin_amdgcn_exp2f(sa[1]);
                            e2.f = __builtin_amdgcn_exp2f(sa[2]);
                            e3.f = __builtin_amdgcn_exp2f(sa[3]);
                            // one v_perm_b32 per pair: truncate-to-bf16 + pack
                            d0 = __builtin_amdgcn_perm(e1.u, e0.u, 0x07060302u);
                            d1 = __builtin_amdgcn_perm(e3.u, e2.u, 0x07060302u);
                        }
                        pkd[set][jth][0] = d0;
                        pkd[set][jth][1] = d1;
                    }
                }
                // ---- assemble PV B-fragments in-register (no LDS) ----
                short8 pb[2];
                #pragma unroll
                for (int set = 0; set < 2; set++) {
                    pun8 u;
                    u.u[0] = pkd[set][0][0]; u.u[1] = pkd[set][0][1];
                    u.u[2] = pkd[set][1][0]; u.u[3] = pkd[set][1][1];
                    pb[set] = u.s8;
                }
                // ---- PV for these 32 keys (permuted key order) ----
                #pragma unroll
                for (int ct = 0; ct < 3; ct++) {
                    const unsigned short* vrow =
                        &Vs[(ct * 16 + col) * VS_STRIDE + s2 * 32 + quad * 4];
                    pun8 uv;
                    uv.u[0] = *(const unsigned*)vrow;
                    uv.u[1] = *(const unsigned*)(vrow + 2);
                    uv.u[2] = *(const unsigned*)(vrow + 16);
                    uv.u[3] = *(const unsigned*)(vrow + 18);
                    short8 va = uv.s8;
                    #pragma unroll
                    for (int set = 0; set < 2; set++)
                        acc_o[set][ct] = __builtin_amdgcn_mfma_f32_16x16x32_bf16(
                            va, pb[set], acc_o[set][ct], 0, 0, 0);
                }
                // ---- l-accumulating tile: row0(ones) dot P = sum(P) ----
                #pragma unroll
                for (int set = 0; set < 2; set++)
                    acc_l[set] = __builtin_amdgcn_mfma_f32_16x16x32_bf16(
                        ones8, pb[set], acc_l[set], 0, 0, 0);
            }
        }
        __syncthreads();   // LDS consumed; next write safe
    }

    // ---- epilogue: l broadcast from quad0/reg0, normalize, us4 stores ----
    #pragma unroll
    for (int set = 0; set < 2; set++) {
        float l = __shfl(acc_l[set][0], col);
        float inv = 1.f / l;
        int gm = gmq[set];
        if (gm < HW) {
            unsigned short* orow = aoT + ((size_t)b * HW + gm) * NC + h * HC;
            #pragma unroll
            for (int ct = 0; ct < 3; ct++) {
                us4 p;
                #pragma unroll
                for (int r = 0; r < 4; r++) p[r] = f2bf(acc_o[set][ct][r] * inv);
                *(us4*)&orow[ct * 16 + quad * 4] = p;
            }
        }
    }
}

// ---------------------------------------------------------------------------
extern "C" void kernel_launch(void* const* d_in, const int* in_sizes, int n_in,
                              void* d_out, int out_size, void* d_ws, size_t ws_size,
                              hipStream_t stream)
{
    const float* x   = (const float*)d_in[0];
    const float* Wq  = (const float*)d_in[1];
    const float* bq  = (const float*)d_in[2];
    const float* Wk  = (const float*)d_in[3];
    const float* bk  = (const float*)d_in[4];
    const float* Wv  = (const float*)d_in[5];
    const float* bv  = (const float*)d_in[6];
    const float* Wo  = (const float*)d_in[7];
    const float* bo  = (const float*)d_in[8];
    const float* dww = (const float*)d_in[9];
    const float* dwb = (const float*)d_in[10];
    const float* lng = (const float*)d_in[11];
    const float* lnb = (const float*)d_in[12];
    const float* pww = (const float*)d_in[13];

    float* out     = (float*)d_out;
    float* y_out   = out;
    float* pos_out = out + (size_t)BATCH * NC * HW;
    float* ref_out = pos_out + (size_t)BATCH * NG * NPTS * 2;

    const size_t NBIG = (size_t)BATCH * NC * HW;    // 9,633,792
    const size_t NSML = (size_t)BATCH * NC * NPTS;  // 2,408,448

    unsigned short* xT   = (unsigned short*)d_ws;
    unsigned short* qT   = xT   + NBIG;
    unsigned short* xsT  = qT   + NBIG;
    unsigned short* kt_w = xsT  + NSML;
    unsigned short* vt_w = kt_w + NSML;
    unsigned short* aoT  = vt_w + NSML;
    unsigned short* wqb  = aoT  + NBIG;
    unsigned short* wob  = wqb + NC * NC;
    unsigned short* wkv  = wob + NC * NC;          // 768 x 384

    transpose_cvt<<<dim3(49, 6, BATCH), 256, 0, stream>>>(x, xT);
    wcvt<<<dim3(144, 4), 256, 0, stream>>>(Wq, Wk, Wv, Wo, wqb, wkv, wob);
    gemm_bf16<2><<<dim3(25, 3, BATCH), 256, 0, stream>>>(
        wqb, bq, nullptr, xT, nullptr, qT, nullptr, HW);
    offset_kernel<<<dim3(196, BATCH * NG), 256, 0, stream>>>(
        qT, dww, dwb, lng, lnb, pww, pos_out, ref_out);
    sample_kernel<<<dim3(98, BATCH * NG), 256, 0, stream>>>(xT, pos_out, xsT);
    gemm_bf16<4><<<dim3(7, 6, BATCH), 256, 0, stream>>>(
        wkv, bk, bv, xsT, nullptr, kt_w, vt_w, NPTS);
    attn_mfma<<<dim3((HW + 127) / 128, BATCH * NH), 256, 0, stream>>>(
        qT, kt_w, vt_w, aoT);
    gemm_bf16<0><<<dim3(25, 3, BATCH), 256, 0, stream>>>(
        wob, bo, nullptr, aoT, y_out, nullptr, nullptr, HW);
}

// Round 6
// 266.627 us; speedup vs baseline: 1.1721x; 1.1721x over previous
//
#include <hip/hip_runtime.h>
#include <math.h>

constexpr int BATCH = 8;
constexpr int NC    = 384;
constexpr int H     = 56, W = 56, HW = 3136;
constexpr int NPTS  = 784;          // 28*28
constexpr int NG    = 4, GC = 96;
constexpr int NH    = 8, HC = 48;

typedef __attribute__((ext_vector_type(8))) short short8;
typedef __attribute__((ext_vector_type(4))) float f32x4;
typedef __attribute__((ext_vector_type(4))) unsigned short us4;

__device__ inline unsigned short f2bf(float f) {       // RNE
    union { float f; unsigned u; } v; v.f = f;
    unsigned r = v.u + 0x7FFF + ((v.u >> 16) & 1);
    return (unsigned short)(r >> 16);
}
__device__ inline float bf2f(unsigned short u) {
    union { unsigned u; float f; } v; v.u = (unsigned)u << 16;
    return v.f;
}
__device__ inline float wred_sum(float v) {
    #pragma unroll
    for (int off = 32; off > 0; off >>= 1) v += __shfl_xor(v, off);
    return v;
}

// ---------------------------------------------------------------------------
// Transpose+convert: x [b][384][3136] fp32 -> xT [b][3136][384] bf16
// ---------------------------------------------------------------------------
__global__ __launch_bounds__(256) void transpose_cvt(
    const float* __restrict__ x, unsigned short* __restrict__ xT)
{
    __shared__ unsigned short Ls[64 * 68];
    int b = blockIdx.z, c0 = blockIdx.y * 64, hw0 = blockIdx.x * 64;
    const float* xb = x + ((size_t)b * NC + c0) * HW + hw0;
    int t = threadIdx.x;
    #pragma unroll
    for (int i = 0; i < 4; i++) {
        int u = t + i * 256;
        int cc = u >> 4, f4 = (u & 15) * 4;
        float4 v = *(const float4*)&xb[(size_t)cc * HW + f4];
        us4 p; p[0] = f2bf(v.x); p[1] = f2bf(v.y); p[2] = f2bf(v.z); p[3] = f2bf(v.w);
        *(us4*)&Ls[cc * 68 + f4] = p;
    }
    __syncthreads();
    unsigned short* xTb = xT + ((size_t)b * HW + hw0) * NC + c0;
    #pragma unroll
    for (int i = 0; i < 4; i++) {
        int u = t + i * 256;
        int hw = u >> 4, cg = (u & 15) * 4;
        us4 p;
        p[0] = Ls[(cg + 0) * 68 + hw];
        p[1] = Ls[(cg + 1) * 68 + hw];
        p[2] = Ls[(cg + 2) * 68 + hw];
        p[3] = Ls[(cg + 3) * 68 + hw];
        *(us4*)&xTb[(size_t)hw * NC + cg] = p;
    }
}

// ---------------------------------------------------------------------------
// Weight convert: Wq -> wqb, Wk -> wkv[0:384], Wv -> wkv[384:768], Wo -> wob
// ---------------------------------------------------------------------------
__global__ __launch_bounds__(256) void wcvt(
    const float* __restrict__ w0, const float* __restrict__ w1,
    const float* __restrict__ w2, const float* __restrict__ w3,
    unsigned short* __restrict__ o0, unsigned short* __restrict__ okv,
    unsigned short* __restrict__ o3)
{
    const float* src; unsigned short* dst;
    switch (blockIdx.y) {
        case 0: src = w0; dst = o0; break;
        case 1: src = w1; dst = okv; break;
        case 2: src = w2; dst = okv + NC * NC; break;
        default: src = w3; dst = o3; break;
    }
    int idx = (blockIdx.x * 256 + threadIdx.x) * 4;
    float4 v = *(const float4*)&src[idx];
    us4 p; p[0] = f2bf(v.x); p[1] = f2bf(v.y); p[2] = f2bf(v.z); p[3] = f2bf(v.w);
    *(us4*)&dst[idx] = p;
}

// ---------------------------------------------------------------------------
// bf16 MFMA GEMM: C[b][m][n] = A[m][k] * BT[b][n][k]^T + bias[m]
// MODE 0: fp32 out [m][n]
// MODE 2: bf16 T-out [n][384]
// MODE 4: fused KV (A is 768 rows): m<384 -> KT[n][384] (bias), m>=384 ->
//         V[m-384][n] (bias2) into Cb2
// v2: register-prefetch pipeline (issue k+1 global loads after the barrier,
// before compute of k).
// ---------------------------------------------------------------------------
template<int MODE>
__global__ __launch_bounds__(256) void gemm_bf16(
    const unsigned short* __restrict__ A, const float* __restrict__ bias,
    const float* __restrict__ bias2, const unsigned short* __restrict__ BT,
    float* __restrict__ Cf, unsigned short* __restrict__ Cb,
    unsigned short* __restrict__ Cb2, int N)
{
    int b  = blockIdx.z;
    int n0 = blockIdx.x * 128;
    int m0 = blockIdx.y * 128;
    const unsigned short* BTb = BT + (size_t)b * N * NC;

    __shared__ unsigned short As[128 * 40];
    __shared__ unsigned short Bs[128 * 40];

    int t = threadIdx.x;
    int wave = t >> 6, lane = t & 63;
    int quad = lane >> 4, col = lane & 15;
    int wm = (wave >> 1) * 64, wn = (wave & 1) * 64;

    const short8 z8 = {0,0,0,0,0,0,0,0};
    f32x4 acc[4][4];
    #pragma unroll
    for (int i = 0; i < 4; i++)
        #pragma unroll
        for (int j = 0; j < 4; j++) acc[i][j] = (f32x4){0.f, 0.f, 0.f, 0.f};

    short8 areg[2], breg[2];
    auto stage_load = [&](int k0) {
        #pragma unroll
        for (int i = 0; i < 2; i++) {
            int u = t + i * 256;
            int mmi = u >> 2, kci = (u & 3) * 8;
            areg[i] = *(const short8*)&A[(size_t)(m0 + mmi) * NC + k0 + kci];
            short8 val = z8;
            if (n0 + mmi < N)
                val = *(const short8*)&BTb[(size_t)(n0 + mmi) * NC + k0 + kci];
            breg[i] = val;
        }
    };

    stage_load(0);
    for (int k0 = 0; k0 < NC; k0 += 32) {
        #pragma unroll
        for (int i = 0; i < 2; i++) {
            int u = t + i * 256;
            int mmi = u >> 2, kci = (u & 3) * 8;
            *(short8*)&As[mmi * 40 + kci] = areg[i];
            *(short8*)&Bs[mmi * 40 + kci] = breg[i];
        }
        __syncthreads();
        if (k0 + 32 < NC) stage_load(k0 + 32);   // prefetch next K-tile

        short8 af[4], bf[4];
        #pragma unroll
        for (int mt = 0; mt < 4; mt++)
            af[mt] = *(const short8*)&As[(wm + mt * 16 + col) * 40 + quad * 8];
        #pragma unroll
        for (int nt = 0; nt < 4; nt++)
            bf[nt] = *(const short8*)&Bs[(wn + nt * 16 + col) * 40 + quad * 8];
        #pragma unroll
        for (int mt = 0; mt < 4; mt++)
            #pragma unroll
            for (int nt = 0; nt < 4; nt++)
                acc[mt][nt] = __builtin_amdgcn_mfma_f32_16x16x32_bf16(
                    af[mt], bf[nt], acc[mt][nt], 0, 0, 0);
        __syncthreads();
    }

    if constexpr (MODE == 0) {
        float* Cfb = Cf + (size_t)b * NC * N;
        #pragma unroll
        for (int mt = 0; mt < 4; mt++) {
            #pragma unroll
            for (int r = 0; r < 4; r++) {
                int m = m0 + wm + mt * 16 + quad * 4 + r;
                float bv = bias[m];
                #pragma unroll
                for (int nt = 0; nt < 4; nt++) {
                    int n = n0 + wn + nt * 16 + col;
                    if (n < N) Cfb[(size_t)m * N + n] = acc[mt][nt][r] + bv;
                }
            }
        }
    } else if constexpr (MODE == 2) {
        unsigned short* Kb = Cb + (size_t)b * N * NC;
        #pragma unroll
        for (int mt = 0; mt < 4; mt++) {
            int mb = m0 + wm + mt * 16 + quad * 4;
            float bv[4];
            #pragma unroll
            for (int r = 0; r < 4; r++) bv[r] = bias[mb + r];
            #pragma unroll
            for (int nt = 0; nt < 4; nt++) {
                int n = n0 + wn + nt * 16 + col;
                if (n < N) {
                    us4 p;
                    #pragma unroll
                    for (int r = 0; r < 4; r++) p[r] = f2bf(acc[mt][nt][r] + bv[r]);
                    *(us4*)&Kb[(size_t)n * NC + mb] = p;
                }
            }
        }
    } else {   // MODE 4: fused KV
        if (m0 < NC) {     // K rows -> KT[n][384]
            unsigned short* Kb = Cb + (size_t)b * N * NC;
            #pragma unroll
            for (int mt = 0; mt < 4; mt++) {
                int mb = m0 + wm + mt * 16 + quad * 4;
                float bv[4];
                #pragma unroll
                for (int r = 0; r < 4; r++) bv[r] = bias[mb + r];
                #pragma unroll
                for (int nt = 0; nt < 4; nt++) {
                    int n = n0 + wn + nt * 16 + col;
                    if (n < N) {
                        us4 p;
                        #pragma unroll
                        for (int r = 0; r < 4; r++) p[r] = f2bf(acc[mt][nt][r] + bv[r]);
                        *(us4*)&Kb[(size_t)n * NC + mb] = p;
                    }
                }
            }
        } else {           // V rows -> V[m-384][n]
            unsigned short* Vb = Cb2 + (size_t)b * NC * N;
            #pragma unroll
            for (int mt = 0; mt < 4; mt++) {
                #pragma unroll
                for (int r = 0; r < 4; r++) {
                    int m = m0 - NC + wm + mt * 16 + quad * 4 + r;
                    float bv = bias2[m];
                    #pragma unroll
                    for (int nt = 0; nt < 4; nt++) {
                        int n = n0 + wn + nt * 16 + col;
                        if (n < N) Vb[(size_t)m * N + n] = f2bf(acc[mt][nt][r] + bv);
                    }
                }
            }
        }
    }
}

// ---------------------------------------------------------------------------
// Offset net, wave-per-point (unchanged)
// ---------------------------------------------------------------------------
__global__ __launch_bounds__(256) void offset_kernel(
    const unsigned short* __restrict__ qT, const float* __restrict__ dww,
    const float* __restrict__ dwb, const float* __restrict__ lng,
    const float* __restrict__ lnb, const float* __restrict__ pww,
    float* __restrict__ pos_out,   float* __restrict__ ref_out)
{
    int wave = threadIdx.x >> 6, l = threadIdx.x & 63;
    int bg = blockIdx.y, b = bg >> 2, g = bg & 3;
    int s  = blockIdx.x * 4 + wave;
    int py = s / 28, px = s - py * 28;
    bool has2 = l < 32;
    int c0 = l, c1 = 64 + l;

    const unsigned short* qb = qT + (size_t)b * HW * NC + g * GC;

    float h0 = 0.f, h1 = 0.f;
    #pragma unroll
    for (int ky = 0; ky < 3; ky++) {
        int yy = py * 2 - 1 + ky;
        if (yy < 0 || yy >= H) continue;
        #pragma unroll
        for (int kx = 0; kx < 3; kx++) {
            int xx = px * 2 - 1 + kx;
            if (xx < 0 || xx >= W) continue;
            const unsigned short* row = qb + (size_t)(yy * W + xx) * NC;
            float w0 = dww[c0 * 9 + ky * 3 + kx];
            h0 = fmaf(bf2f(row[c0]), w0, h0);
            if (has2) {
                float w1 = dww[c1 * 9 + ky * 3 + kx];
                h1 = fmaf(bf2f(row[c1]), w1, h1);
            }
        }
    }
    h0 += dwb[c0];
    if (has2) h1 += dwb[c1];

    float mu = wred_sum(h0 + (has2 ? h1 : 0.f)) * (1.f / GC);
    float d0 = h0 - mu, d1 = h1 - mu;
    float var = wred_sum(d0 * d0 + (has2 ? d1 * d1 : 0.f)) * (1.f / GC);
    float rstd = rsqrtf(var + 1e-5f);

    float hn0 = d0 * rstd * lng[c0] + lnb[c0];
    float ge0 = 0.5f * hn0 * (1.f + erff(hn0 * 0.70710678118654752f));
    float ge1 = 0.f;
    if (has2) {
        float hn1 = d1 * rstd * lng[c1] + lnb[c1];
        ge1 = 0.5f * hn1 * (1.f + erff(hn1 * 0.70710678118654752f));
    }

    float offy = wred_sum(ge0 * pww[c0] + (has2 ? ge1 * pww[c1] : 0.f));
    float offx = wred_sum(ge0 * pww[GC + c0] + (has2 ? ge1 * pww[GC + c1] : 0.f));

    if (l == 0) {
        float ry = (2.f * py + 1.f) / 27.f - 1.f;
        float rx = (2.f * px + 1.f) / 27.f - 1.f;
        size_t idx = ((size_t)bg * NPTS + s) * 2;
        pos_out[idx]     = tanhf(offy) * (1.f / 27.f) + ry;
        pos_out[idx + 1] = tanhf(offx) * (1.f / 27.f) + rx;
        ref_out[idx]     = ry;
        ref_out[idx + 1] = rx;
    }
}

// ---------------------------------------------------------------------------
// Bilinear grid sample from xT (bf16, [b][hw][384]) -> xsT [b][pt][384] bf16.
// v2: us4 vector loads (24 active lanes x 8B).
// ---------------------------------------------------------------------------
__global__ __launch_bounds__(256) void sample_kernel(
    const unsigned short* __restrict__ xT, const float* __restrict__ pos,
    unsigned short* __restrict__ xsT)
{
    int bg = blockIdx.y;
    int b  = bg >> 2, g = bg & 3;
    int s  = blockIdx.x * 8 + (threadIdx.x >> 5);
    int l  = threadIdx.x & 31;

    const float* pg = pos + ((size_t)bg * NPTS + s) * 2;
    float py = pg[0], px = pg[1];
    float gx = (px + 1.f) * 27.5f;
    float gy = (py + 1.f) * 27.5f;
    float x0f = floorf(gx), y0f = floorf(gy);
    int ix0 = (int)x0f, iy0 = (int)y0f;
    int ix1 = ix0 + 1,  iy1 = iy0 + 1;
    float wx1 = gx - x0f, wx0 = 1.f - wx1;
    float wy1 = gy - y0f, wy0 = 1.f - wy1;
    bool vx0 = (ix0 >= 0) && (ix0 < W);
    bool vx1 = (ix1 >= 0) && (ix1 < W);
    bool vy0 = (iy0 >= 0) && (iy0 < H);
    bool vy1 = (iy1 >= 0) && (iy1 < H);
    int cx0 = vx0 ? ix0 : 0, cx1 = vx1 ? ix1 : 0;
    int cy0 = vy0 ? iy0 : 0, cy1 = vy1 ? iy1 : 0;
    float w00 = (vx0 && vy0) ? wx0 * wy0 : 0.f;
    float w01 = (vx1 && vy0) ? wx1 * wy0 : 0.f;
    float w10 = (vx0 && vy1) ? wx0 * wy1 : 0.f;
    float w11 = (vx1 && vy1) ? wx1 * wy1 : 0.f;

    if (l < 24) {
        const unsigned short* xb = xT + (size_t)b * HW * NC + g * GC;
        const unsigned short* r00 = xb + (size_t)(cy0 * W + cx0) * NC + l * 4;
        const unsigned short* r01 = xb + (size_t)(cy0 * W + cx1) * NC + l * 4;
        const unsigned short* r10 = xb + (size_t)(cy1 * W + cx0) * NC + l * 4;
        const unsigned short* r11 = xb + (size_t)(cy1 * W + cx1) * NC + l * 4;
        us4 a00 = *(const us4*)r00;
        us4 a01 = *(const us4*)r01;
        us4 a10 = *(const us4*)r10;
        us4 a11 = *(const us4*)r11;
        us4 o;
        #pragma unroll
        for (int j = 0; j < 4; j++) {
            float val = bf2f(a00[j]) * w00 + bf2f(a01[j]) * w01
                      + bf2f(a10[j]) * w10 + bf2f(a11[j]) * w11;
            o[j] = f2bf(val);
        }
        *(us4*)&xsT[((size_t)b * NPTS + s) * NC + g * GC + l * 4] = o;
    }
}

// ---------------------------------------------------------------------------
// Fused flash attention v11: v10 with KS_STRIDE reverted 60 -> 56.
// R5 post-mortem: 60 shorts = 120 B row stride is NOT 16B-aligned, so every
// short8 (ds_*_b128) K access at odd row landed at addr==8 (mod 16) and was
// split by HW -> attn 81->108us despite VALU and bank-conflict improvements
// landing as predicted. LDS strides must stay multiples of 8 shorts.
// Kept from v10: raw v_exp_f32 (__builtin_amdgcn_exp2f) — VALUBusy 60->23%
// confirmed the ocml exp2f range-handling was the dominant VALU consumer.
// ---------------------------------------------------------------------------
#define KS_STRIDE 56    // shorts: 48 chans + 8 pad (112 B, 16B-aligned)
#define VS_STRIDE 136   // shorts: 128 keys + 8 pad

__device__ inline short8 scale8(short8 v, float s) {
    short8 r;
    #pragma unroll
    for (int j = 0; j < 8; j++) {
        unsigned short b = (unsigned short)v[j];
        r[j] = (short)f2bf(bf2f(b) * s);
    }
    return r;
}

union pun8 { short8 s8; unsigned u[4]; };

__global__ __launch_bounds__(256) void attn_mfma(
    const unsigned short* __restrict__ qT, const unsigned short* __restrict__ kt,
    const unsigned short* __restrict__ vt, unsigned short* __restrict__ aoT)
{
    __shared__ __align__(16) unsigned short smem[128 * KS_STRIDE + 48 * VS_STRIDE];
    unsigned short* Ks = smem;                 // 128*56 = 7168 shorts
    unsigned short* Vs = Ks + 128 * KS_STRIDE; // 48*136 = 6528 shorts

    int t    = threadIdx.x;
    int wave = t >> 6, lane = t & 63;
    int quad = lane >> 4, col = lane & 15;

    int bh = blockIdx.y;
    int b  = bh >> 3, h = bh & 7;
    int m0 = blockIdx.x * 128;
    const unsigned short* KT = kt + (size_t)b * NPTS * NC + h * HC;
    const unsigned short* VT = vt + ((size_t)b * NC + h * HC) * NPTS;

    // 48^-0.5 * log2(e): QK MFMA then computes S*scale*log2e, so exp2(S') = exp(S*scale)
    const float scale = 0.14433756729740643f * 1.4426950408889634f;
    const short8 z8 = {0,0,0,0,0,0,0,0};

    // ---- ones-row A fragment for the l-accumulating PV tile ----
    short ones_v = (col == 0) ? (short)0x3F80 : (short)0;
    short8 ones8 = {ones_v, ones_v, ones_v, ones_v, ones_v, ones_v, ones_v, ones_v};

    // ---- Q B-fragments, 2 sets, pre-scaled ----
    int gmq[2];
    short8 qb0[2], qb1[2];
    #pragma unroll
    for (int set = 0; set < 2; set++) {
        int gm = m0 + wave * 32 + set * 16 + col;
        gmq[set] = gm;
        int cg = gm < HW ? gm : HW - 1;
        const unsigned short* r0 = qT + ((size_t)b * HW + cg) * NC + h * HC;
        qb0[set] = scale8(*(const short8*)&r0[quad * 8], scale);
        qb1[set] = (quad < 2) ? scale8(*(const short8*)&r0[32 + quad * 8], scale) : z8;
    }

    f32x4 acc_l[2];
    f32x4 acc_o[2][3];
    #pragma unroll
    for (int set = 0; set < 2; set++) {
        acc_l[set] = (f32x4){0.f, 0.f, 0.f, 0.f};
        #pragma unroll
        for (int ct = 0; ct < 3; ct++) acc_o[set][ct] = (f32x4){0.f, 0.f, 0.f, 0.f};
    }

    // staging identity: K key = t>>1 (0..127), parts (t&1)*3 ..+2
    int skey  = t >> 1;
    int spart = (t & 1) * 3;
    short8 kreg[3], vreg[3];

    // ---- prologue: load chunk 0 ----
    {
        const unsigned short* krow = KT + (size_t)skey * NC + spart * 8;
        #pragma unroll
        for (int i = 0; i < 3; i++) kreg[i] = *(const short8*)(krow + i * 8);
        #pragma unroll
        for (int i = 0; i < 3; i++) {
            int li = t + i * 256;
            int chan = li >> 4, part = li & 15;
            vreg[i] = *(const short8*)&VT[(size_t)chan * NPTS + part * 8];
        }
    }

    for (int ci = 0; ci < 7; ci++) {
        int k0 = ci * 128;

        // ---- write staged regs -> LDS ----
        #pragma unroll
        for (int i = 0; i < 3; i++)
            *(short8*)&Ks[skey * KS_STRIDE + (spart + i) * 8] = kreg[i];
        #pragma unroll
        for (int i = 0; i < 3; i++) {
            int li = t + i * 256;
            int chan = li >> 4, part = li & 15;
            *(short8*)&Vs[chan * VS_STRIDE + part * 8] = vreg[i];
        }
        __syncthreads();

        // ---- issue next chunk's global loads (latency hidden by compute) --
        if (ci < 6) {
            int nk0 = k0 + 128;
            bool kv = nk0 + skey < NPTS;
            const unsigned short* krow = KT + (size_t)(nk0 + skey) * NC + spart * 8;
            #pragma unroll
            for (int i = 0; i < 3; i++) kreg[i] = kv ? *(const short8*)(krow + i * 8) : z8;
            #pragma unroll
            for (int i = 0; i < 3; i++) {
                int li = t + i * 256;
                int chan = li >> 4, part = li & 15;
                vreg[i] = (nk0 + part * 8 < NPTS)
                    ? *(const short8*)&VT[(size_t)chan * NPTS + nk0 + part * 8] : z8;
            }
        }

        // ---- compute chunk ci ----
        #pragma unroll
        for (int s2 = 0; s2 < 4; s2++) {
            if (k0 + s2 * 32 < NPTS) {     // tail guard: skip dead 32-key steps
                unsigned pkd[2][2][2];
                #pragma unroll
                for (int jth = 0; jth < 2; jth++) {
                    int jt = s2 * 2 + jth;
                    int keyl = jt * 16 + col;
                    short8 kb0 = *(const short8*)&Ks[keyl * KS_STRIDE + quad * 8];
                    short8 kb1 = (quad < 2)
                        ? *(const short8*)&Ks[keyl * KS_STRIDE + 32 + quad * 8] : z8;
                    bool valid = (k0 + jt * 16) < NPTS;     // tile-uniform
                    #pragma unroll
                    for (int set = 0; set < 2; set++) {
                        f32x4 sa = {0.f, 0.f, 0.f, 0.f};
                        sa = __builtin_amdgcn_mfma_f32_16x16x32_bf16(kb0, qb0[set], sa, 0, 0, 0);
                        sa = __builtin_amdgcn_mfma_f32_16x16x32_bf16(kb1, qb1[set], sa, 0, 0, 0);
                        unsigned d0 = 0, d1 = 0;
                        if (valid) {
                            union { float f; unsigned u; } e0, e1, e2, e3;
                            e0.f = __builtin_amdgcn_exp2f(sa[0]);   // raw v_exp_f32
                            e1.f = __builtin_amdgcn_exp2f(sa[1]);
                            e2.f = __builtin_amdgcn_exp2f(sa[2]);
                            e3.f = __builtin_amdgcn_exp2f(sa[3]);
                            // one v_perm_b32 per pair: truncate-to-bf16 + pack
                            d0 = __builtin_amdgcn_perm(e1.u, e0.u, 0x07060302u);
                            d1 = __builtin_amdgcn_perm(e3.u, e2.u, 0x07060302u);
                        }
                        pkd[set][jth][0] = d0;
                        pkd[set][jth][1] = d1;
                    }
                }
                // ---- assemble PV B-fragments in-register (no LDS) ----
                short8 pb[2];
                #pragma unroll
                for (int set = 0; set < 2; set++) {
                    pun8 u;
                    u.u[0] = pkd[set][0][0]; u.u[1] = pkd[set][0][1];
                    u.u[2] = pkd[set][1][0]; u.u[3] = pkd[set][1][1];
                    pb[set] = u.s8;
                }
                // ---- PV for these 32 keys (permuted key order) ----
                #pragma unroll
                for (int ct = 0; ct < 3; ct++) {
                    const unsigned short* vrow =
                        &Vs[(ct * 16 + col) * VS_STRIDE + s2 * 32 + quad * 4];
                    pun8 uv;
                    uv.u[0] = *(const unsigned*)vrow;
                    uv.u[1] = *(const unsigned*)(vrow + 2);
                    uv.u[2] = *(const unsigned*)(vrow + 16);
                    uv.u[3] = *(const unsigned*)(vrow + 18);
                    short8 va = uv.s8;
                    #pragma unroll
                    for (int set = 0; set < 2; set++)
                        acc_o[set][ct] = __builtin_amdgcn_mfma_f32_16x16x32_bf16(
                            va, pb[set], acc_o[set][ct], 0, 0, 0);
                }
                // ---- l-accumulating tile: row0(ones) dot P = sum(P) ----
                #pragma unroll
                for (int set = 0; set < 2; set++)
                    acc_l[set] = __builtin_amdgcn_mfma_f32_16x16x32_bf16(
                        ones8, pb[set], acc_l[set], 0, 0, 0);
            }
        }
        __syncthreads();   // LDS consumed; next write safe
    }

    // ---- epilogue: l broadcast from quad0/reg0, normalize, us4 stores ----
    #pragma unroll
    for (int set = 0; set < 2; set++) {
        float l = __shfl(acc_l[set][0], col);
        float inv = 1.f / l;
        int gm = gmq[set];
        if (gm < HW) {
            unsigned short* orow = aoT + ((size_t)b * HW + gm) * NC + h * HC;
            #pragma unroll
            for (int ct = 0; ct < 3; ct++) {
                us4 p;
                #pragma unroll
                for (int r = 0; r < 4; r++) p[r] = f2bf(acc_o[set][ct][r] * inv);
                *(us4*)&orow[ct * 16 + quad * 4] = p;
            }
        }
    }
}

// ---------------------------------------------------------------------------
extern "C" void kernel_launch(void* const* d_in, const int* in_sizes, int n_in,
                              void* d_out, int out_size, void* d_ws, size_t ws_size,
                              hipStream_t stream)
{
    const float* x   = (const float*)d_in[0];
    const float* Wq  = (const float*)d_in[1];
    const float* bq  = (const float*)d_in[2];
    const float* Wk  = (const float*)d_in[3];
    const float* bk  = (const float*)d_in[4];
    const float* Wv  = (const float*)d_in[5];
    const float* bv  = (const float*)d_in[6];
    const float* Wo  = (const float*)d_in[7];
    const float* bo  = (const float*)d_in[8];
    const float* dww = (const float*)d_in[9];
    const float* dwb = (const float*)d_in[10];
    const float* lng = (const float*)d_in[11];
    const float* lnb = (const float*)d_in[12];
    const float* pww = (const float*)d_in[13];

    float* out     = (float*)d_out;
    float* y_out   = out;
    float* pos_out = out + (size_t)BATCH * NC * HW;
    float* ref_out = pos_out + (size_t)BATCH * NG * NPTS * 2;

    const size_t NBIG = (size_t)BATCH * NC * HW;    // 9,633,792
    const size_t NSML = (size_t)BATCH * NC * NPTS;  // 2,408,448

    unsigned short* xT   = (unsigned short*)d_ws;
    unsigned short* qT   = xT   + NBIG;
    unsigned short* xsT  = qT   + NBIG;
    unsigned short* kt_w = xsT  + NSML;
    unsigned short* vt_w = kt_w + NSML;
    unsigned short* aoT  = vt_w + NSML;
    unsigned short* wqb  = aoT  + NBIG;
    unsigned short* wob  = wqb + NC * NC;
    unsigned short* wkv  = wob + NC * NC;          // 768 x 384

    transpose_cvt<<<dim3(49, 6, BATCH), 256, 0, stream>>>(x, xT);
    wcvt<<<dim3(144, 4), 256, 0, stream>>>(Wq, Wk, Wv, Wo, wqb, wkv, wob);
    gemm_bf16<2><<<dim3(25, 3, BATCH), 256, 0, stream>>>(
        wqb, bq, nullptr, xT, nullptr, qT, nullptr, HW);
    offset_kernel<<<dim3(196, BATCH * NG), 256, 0, stream>>>(
        qT, dww, dwb, lng, lnb, pww, pos_out, ref_out);
    sample_kernel<<<dim3(98, BATCH * NG), 256, 0, stream>>>(xT, pos_out, xsT);
    gemm_bf16<4><<<dim3(7, 6, BATCH), 256, 0, stream>>>(
        wkv, bk, bv, xsT, nullptr, kt_w, vt_w, NPTS);
    attn_mfma<<<dim3((HW + 127) / 128, BATCH * NH), 256, 0, stream>>>(
        qT, kt_w, vt_w, aoT);
    gemm_bf16<0><<<dim3(25, 3, BATCH), 256, 0, stream>>>(
        wob, bo, nullptr, aoT, y_out, nullptr, nullptr, HW);
}